// Round 2
// baseline (1364.407 us; speedup 1.0000x reference)
//
#include <hip/hip_runtime.h>
#include <math.h>

// Shapes
#define BB  512
#define SS  23
#define DD  768
#define EE  8
#define NHH 8
#define RR  256
#define HDD 32
#define LL  50
#define HH2 384            // D/2
#define TT  (BB*SS)        // 11776
#define LN_EPS 1e-5f

// block-wide sum; `red` must have >= nw floats; safe to call repeatedly
__device__ __forceinline__ float block_sum(float v, float* red, int nw){
  #pragma unroll
  for (int o = 32; o > 0; o >>= 1) v += __shfl_down(v, o, 64);
  int wid = threadIdx.x >> 6;
  __syncthreads();                       // protect red from previous use
  if ((threadIdx.x & 63) == 0) red[wid] = v;
  __syncthreads();
  float s = 0.f;
  for (int i = 0; i < nw; ++i) s += red[i];
  return s;
}

// ---------------- K1: masked-mean context [B,D] ----------------
__global__ void k_context(const float* __restrict__ emb, const int* __restrict__ existing,
                          float* __restrict__ ctx){
  int b = blockIdx.x, tid = threadIdx.x;
  float acc0=0.f, acc1=0.f, acc2=0.f;
  int cnt = 0;
  for (int s = 0; s < SS; ++s){
    if (existing[b*SS + s]){
      ++cnt;
      const float* row = emb + ((size_t)(b*SS + s))*DD;
      acc0 += row[tid]; acc1 += row[tid+256]; acc2 += row[tid+512];
    }
  }
  float inv = 1.0f / ((float)cnt + 1e-8f);
  ctx[(size_t)b*DD + tid      ] = acc0*inv;
  ctx[(size_t)b*DD + tid + 256] = acc1*inv;
  ctx[(size_t)b*DD + tid + 512] = acc2*inv;
}

// ---------------- K2: DPE -> pos [S,E,D] (depends only on s) ----------------
__global__ void k_pos(const float* __restrict__ mt,
                      const float* __restrict__ w0, const float* __restrict__ bi0,
                      const float* __restrict__ w1, const float* __restrict__ bi1,
                      const float* __restrict__ w2, const float* __restrict__ bi2,
                      const float* __restrict__ wo, const float* __restrict__ bo,
                      const float* __restrict__ lng, const float* __restrict__ lnb,
                      float* __restrict__ pos){
  int s = blockIdx.x / EE, e = blockIdx.x % EE, tid = threadIdx.x;
  __shared__ float def[DD];
  __shared__ float hA[RR], hB[RR];
  __shared__ float red[8];
  for (int j = tid; j < DD; j += 256) def[j] = mt[s*DD + j];
  __syncthreads();
  // h0 = relu(def @ w0[e] + b0)
  float acc = 0.f;
  { const float* W = w0 + (size_t)e*DD*RR;
    for (int d = 0; d < DD; ++d) acc += def[d] * W[(size_t)d*RR + tid]; }
  hA[tid] = fmaxf(acc + bi0[e*RR + tid], 0.f);
  __syncthreads();
  acc = 0.f;
  { const float* W = w1 + (size_t)e*RR*RR;
    for (int kk = 0; kk < RR; ++kk) acc += hA[kk] * W[kk*RR + tid]; }
  hB[tid] = fmaxf(acc + bi1[e*RR + tid], 0.f);
  __syncthreads();
  acc = 0.f;
  { const float* W = w2 + (size_t)e*RR*RR;
    for (int kk = 0; kk < RR; ++kk) acc += hB[kk] * W[kk*RR + tid]; }
  __syncthreads();
  hA[tid] = fmaxf(acc + bi2[e*RR + tid], 0.f);
  __syncthreads();
  // out = h2 @ wo[e] + bo + def ; LN over D
  float o[3];
  const float* Wo = wo + (size_t)e*RR*DD;
  #pragma unroll
  for (int j = 0; j < 3; ++j){
    int d = tid + j*256;
    float a = 0.f;
    for (int kk = 0; kk < RR; ++kk) a += hA[kk] * Wo[(size_t)kk*DD + d];
    o[j] = a + bo[e*DD + d] + def[d];
  }
  float mean = block_sum(o[0]+o[1]+o[2], red, 4) * (1.f/DD);
  float dv = 0.f;
  #pragma unroll
  for (int j = 0; j < 3; ++j){ float c = o[j]-mean; dv += c*c; }
  float rstd = rsqrtf(block_sum(dv, red, 4) * (1.f/DD) + LN_EPS);
  #pragma unroll
  for (int j = 0; j < 3; ++j){
    int d = tid + j*256;
    pos[((size_t)(s*EE + e))*DD + d] =
      (o[j]-mean)*rstd*lng[e*DD + d] + lnb[e*DD + d];
  }
}

// ---------------- K2b: posF/posG [S,E,R] ----------------
__global__ void k_posFG(const float* __restrict__ pos,
                        const float* __restrict__ fw1p, const float* __restrict__ gw1p,
                        float* __restrict__ posF, float* __restrict__ posG){
  int s = blockIdx.x / EE, e = blockIdx.x % EE, tid = threadIdx.x;
  __shared__ float p[DD];
  for (int j = tid; j < DD; j += 256) p[j] = pos[((size_t)(s*EE + e))*DD + j];
  __syncthreads();
  float aF = 0.f, aG = 0.f;
  const float* WF = fw1p + (size_t)e*DD*RR;
  const float* WG = gw1p + (size_t)e*DD*RR;
  for (int d = 0; d < DD; ++d){
    float pv = p[d];
    aF += pv * WF[(size_t)d*RR + tid];
    aG += pv * WG[(size_t)d*RR + tid];
  }
  posF[(s*EE + e)*RR + tid] = aF;
  posG[(s*EE + e)*RR + tid] = aG;
}

// ---------------- K2c: router default half [S,R] ----------------
__global__ void k_rtrD(const float* __restrict__ mt, const float* __restrict__ rw1,
                       float* __restrict__ rtrD){
  int s = blockIdx.x, tid = threadIdx.x;
  __shared__ float def[DD];
  for (int j = tid; j < DD; j += 256) def[j] = mt[s*DD + j];
  __syncthreads();
  float a = 0.f;
  for (int d = 0; d < DD; ++d) a += def[d] * rw1[(size_t)d*RR + tid];
  rtrD[s*RR + tid] = a;
}

// ---------------- K3: ctxF/ctxG [B,E,R], 8 b per block ----------------
__global__ void k_ctxFG(const float* __restrict__ ctx,
                        const float* __restrict__ fw1c, const float* __restrict__ gw1c,
                        float* __restrict__ ctxF, float* __restrict__ ctxG){
  int b0 = (blockIdx.x / EE) * 8;
  int e  = blockIdx.x % EE;
  int tid = threadIdx.x;
  __shared__ float c[8][DD];
  for (int i = 0; i < 8; ++i)
    for (int j = tid; j < DD; j += 256) c[i][j] = ctx[(size_t)(b0+i)*DD + j];
  __syncthreads();
  float aF[8] = {0,0,0,0,0,0,0,0}, aG[8] = {0,0,0,0,0,0,0,0};
  const float* WF = fw1c + (size_t)e*DD*RR;
  const float* WG = gw1c + (size_t)e*DD*RR;
  for (int d = 0; d < DD; ++d){
    float wf = WF[(size_t)d*RR + tid];
    float wg = WG[(size_t)d*RR + tid];
    #pragma unroll
    for (int i = 0; i < 8; ++i){ aF[i] += c[i][d]*wf; aG[i] += c[i][d]*wg; }
  }
  #pragma unroll
  for (int i = 0; i < 8; ++i){
    ctxF[((size_t)(b0+i)*EE + e)*RR + tid] = aF[i];
    ctxG[((size_t)(b0+i)*EE + e)*RR + tid] = aG[i];
  }
}

// ---------------- K3b: router ctx half [B,R], 8 b per block ----------------
__global__ void k_rtrC(const float* __restrict__ ctx, const float* __restrict__ rw1,
                       float* __restrict__ rtrC){
  int b0 = blockIdx.x * 8, tid = threadIdx.x;
  __shared__ float c[8][DD];
  for (int i = 0; i < 8; ++i)
    for (int j = tid; j < DD; j += 256) c[i][j] = ctx[(size_t)(b0+i)*DD + j];
  __syncthreads();
  float a[8] = {0,0,0,0,0,0,0,0};
  const float* W = rw1 + (size_t)DD*RR;   // rows D..2D-1
  for (int d = 0; d < DD; ++d){
    float w = W[(size_t)d*RR + tid];
    #pragma unroll
    for (int i = 0; i < 8; ++i) a[i] += c[i][d]*w;
  }
  #pragma unroll
  for (int i = 0; i < 8; ++i) rtrC[(size_t)(b0+i)*RR + tid] = a[i];
}

// ---------------- K4: router softmax + top2 ----------------
__global__ void k_router(const float* __restrict__ rtrD, const float* __restrict__ rtrC,
                         const float* __restrict__ rb1, const float* __restrict__ rw2,
                         const float* __restrict__ rb2,
                         float* __restrict__ topv, int* __restrict__ topi){
  int t = blockIdx.x, b = t / SS, s = t % SS, tid = threadIdx.x;
  __shared__ float red[8];
  __shared__ float sc[EE];
  float hr = fmaxf(rtrD[s*RR + tid] + rtrC[(size_t)b*RR + tid] + rb1[tid], 0.f);
  for (int e = 0; e < EE; ++e){
    float ssum = block_sum(hr * rw2[tid*EE + e], red, 4);
    if (tid == 0) sc[e] = ssum + rb2[e];
  }
  if (tid == 0){
    float m = -1e30f;
    for (int e = 0; e < EE; ++e) m = fmaxf(m, sc[e]);
    float w[EE]; float Z = 0.f;
    for (int e = 0; e < EE; ++e){ w[e] = expf(sc[e]-m); Z += w[e]; }
    int i0 = 0;
    for (int e = 1; e < EE; ++e) if (w[e] > w[i0]) i0 = e;
    int i1 = -1;
    for (int e = 0; e < EE; ++e) if (e != i0 && (i1 < 0 || w[e] > w[i1])) i1 = e;
    float iz = 1.f/Z;
    topv[t*2] = w[i0]*iz; topv[t*2+1] = w[i1]*iz;
    topi[t*2] = i0;       topi[t*2+1] = i1;
  }
}

// ---------------- K5: sparse expert eval -> sec [T,D] fp32 ----------------
__global__ void k_sec(const float* __restrict__ emb, const int* __restrict__ existing,
                      const float* __restrict__ ctx,
                      const float* __restrict__ ctxF, const float* __restrict__ ctxG,
                      const float* __restrict__ posF, const float* __restrict__ posG,
                      const float* __restrict__ fb1, const float* __restrict__ fw2,
                      const float* __restrict__ fb2,
                      const float* __restrict__ gb1, const float* __restrict__ gw2,
                      const float* __restrict__ gb2,
                      const float* __restrict__ elng, const float* __restrict__ elnb,
                      const float* __restrict__ topv, const int* __restrict__ topi,
                      float* __restrict__ sec){
  int t = blockIdx.x, b = t / SS, s = t % SS, tid = threadIdx.x;
  size_t base = (size_t)t * DD;
  if (existing[t]){
    for (int j = tid; j < DD; j += 256) sec[base + j] = emb[base + j];
    return;
  }
  __shared__ float hf[RR];
  __shared__ float red[8];
  float out[3] = {0.f, 0.f, 0.f};
  for (int j = 0; j < 2; ++j){
    int e = topi[t*2 + j];
    float sw = topv[t*2 + j];
    float hfv = fmaxf(ctxF[((size_t)b*EE + e)*RR + tid] + posF[(s*EE + e)*RR + tid]
                      + fb1[e*RR + tid], 0.f);
    float hgv = fmaxf(ctxG[((size_t)b*EE + e)*RR + tid] + posG[(s*EE + e)*RR + tid]
                      + gb1[e*RR + tid], 0.f);
    hf[tid] = hfv;                                   // block_sum barriers order this
    float gsum = block_sum(hgv * gw2[e*RR + tid], red, 4);
    float gate = 1.f / (1.f + expf(-(gsum + gb2[e])));
    // cand = hf @ fus_w2[e] + fb2 ; mix ; LN
    const float* W = fw2 + (size_t)e*RR*DD;
    float mix[3]; float lsum = 0.f;
    #pragma unroll
    for (int jj = 0; jj < 3; ++jj){
      int d = tid + jj*256;
      float a = 0.f;
      for (int kk = 0; kk < RR; ++kk) a += hf[kk] * W[(size_t)kk*DD + d];
      a += fb2[e*DD + d];
      float m = gate*a + (1.f-gate)*ctx[(size_t)b*DD + d];
      mix[jj] = m; lsum += m;
    }
    float mean = block_sum(lsum, red, 4) * (1.f/DD);
    float dv = 0.f;
    #pragma unroll
    for (int jj = 0; jj < 3; ++jj){ float c = mix[jj]-mean; dv += c*c; }
    float rstd = rsqrtf(block_sum(dv, red, 4) * (1.f/DD) + LN_EPS);
    #pragma unroll
    for (int jj = 0; jj < 3; ++jj){
      int d = tid + jj*256;
      out[jj] += sw * ((mix[jj]-mean)*rstd*elng[e*DD + d] + elnb[e*DD + d]);
    }
  }
  #pragma unroll
  for (int jj = 0; jj < 3; ++jj) sec[base + tid + jj*256] = out[jj];
}

// ---------------- K6: x1 = gelu(sec @ red_w1 + b1) [T,384], 4 tokens/block ----------------
__global__ void k_red1(const float* __restrict__ sec, const float* __restrict__ w1,
                       const float* __restrict__ b1v, float* __restrict__ x1){
  int t0 = blockIdx.x * 4, tid = threadIdx.x;   // 384 threads
  __shared__ float sx[4][DD];
  for (int i = 0; i < 4; ++i)
    for (int j = tid; j < DD; j += 384) sx[i][j] = sec[(size_t)(t0+i)*DD + j];
  __syncthreads();
  float a[4] = {0,0,0,0};
  for (int d = 0; d < DD; ++d){
    float w = w1[(size_t)d*HH2 + tid];
    #pragma unroll
    for (int i = 0; i < 4; ++i) a[i] += sx[i][d]*w;
  }
  float bb = b1v[tid];
  #pragma unroll
  for (int i = 0; i < 4; ++i){
    float v = a[i] + bb;
    x1[(size_t)(t0+i)*HH2 + tid] = 0.5f*v*(1.f + erff(v*0.70710678118654752f));
  }
}

// ---------------- K7: x = LN(gelu(x1 @ red_w2 + b2)) [T,256], 4 tokens/block ----------------
__global__ void k_red2(const float* __restrict__ x1, const float* __restrict__ w2,
                       const float* __restrict__ b2v, const float* __restrict__ lng,
                       const float* __restrict__ lnb, float* __restrict__ xr){
  int t0 = blockIdx.x * 4, tid = threadIdx.x;
  __shared__ float sx[4][HH2];
  __shared__ float red[8];
  for (int i = 0; i < 4; ++i)
    for (int j = tid; j < HH2; j += 256) sx[i][j] = x1[(size_t)(t0+i)*HH2 + j];
  __syncthreads();
  float a[4] = {0,0,0,0};
  for (int d = 0; d < HH2; ++d){
    float w = w2[(size_t)d*RR + tid];
    #pragma unroll
    for (int i = 0; i < 4; ++i) a[i] += sx[i][d]*w;
  }
  float bb = b2v[tid];
  float g = lng[tid], be = lnb[tid];
  for (int i = 0; i < 4; ++i){
    float v = a[i] + bb;
    v = 0.5f*v*(1.f + erff(v*0.70710678118654752f));
    float mean = block_sum(v, red, 4) * (1.f/RR);
    float c = v - mean;
    float rstd = rsqrtf(block_sum(c*c, red, 4) * (1.f/RR) + LN_EPS);
    xr[(size_t)(t0+i)*RR + tid] = (v-mean)*rstd*g + be;
  }
}

// ---------------- K8: QKV [T,R] each, 4 tokens/block ----------------
__global__ void k_qkv(const float* __restrict__ xr, const float* __restrict__ qkvw,
                      const float* __restrict__ qkvb,
                      float* __restrict__ q, float* __restrict__ k, float* __restrict__ v){
  int t0 = blockIdx.x * 4, tid = threadIdx.x;
  __shared__ float sx[4][RR];
  for (int i = 0; i < 4; ++i) sx[i][tid] = xr[(size_t)(t0+i)*RR + tid];
  __syncthreads();
  float* outs[3] = {q, k, v};
  for (int m = 0; m < 3; ++m){
    const float* W = qkvw + (size_t)m*RR*RR;
    float a[4] = {0,0,0,0};
    for (int d = 0; d < RR; ++d){
      float w = W[(size_t)d*RR + tid];
      #pragma unroll
      for (int i = 0; i < 4; ++i) a[i] += sx[i][d]*w;
    }
    float bb = qkvb[m*RR + tid];
    #pragma unroll
    for (int i = 0; i < 4; ++i) outs[m][(size_t)(t0+i)*RR + tid] = a[i] + bb;
  }
}

// ---------------- K9: attention per (b,head) ----------------
__global__ void k_attn(const float* __restrict__ q, const float* __restrict__ k,
                       const float* __restrict__ v, float* __restrict__ o){
  int bh = blockIdx.x, b = bh / NHH, h = bh % NHH, tid = threadIdx.x;
  __shared__ float qs[SS][HDD], ks[SS][HDD], vs[SS][HDD];
  __shared__ float scr[SS][SS+1];
  for (int idx = tid; idx < SS*HDD; idx += 256){
    int s = idx / HDD, d = idx % HDD;
    size_t g = ((size_t)(b*SS + s))*RR + h*HDD + d;
    qs[s][d] = q[g]; ks[s][d] = k[g]; vs[s][d] = v[g];
  }
  __syncthreads();
  const float scale = 0.17677669529663687f;  // 1/sqrt(32)
  for (int idx = tid; idx < SS*SS; idx += 256){
    int qi = idx / SS, ki = idx % SS;
    float a = 0.f;
    #pragma unroll
    for (int d = 0; d < HDD; ++d) a += qs[qi][d]*ks[ki][d];
    scr[qi][ki] = a*scale;
  }
  __syncthreads();
  if (tid < SS){
    float m = -1e30f;
    for (int ki = 0; ki < SS; ++ki) m = fmaxf(m, scr[tid][ki]);
    float Z = 0.f;
    for (int ki = 0; ki < SS; ++ki){ float e2 = expf(scr[tid][ki]-m); scr[tid][ki] = e2; Z += e2; }
    float iz = 1.f/Z;
    for (int ki = 0; ki < SS; ++ki) scr[tid][ki] *= iz;
  }
  __syncthreads();
  for (int idx = tid; idx < SS*HDD; idx += 256){
    int qi = idx / HDD, d = idx % HDD;
    float a = 0.f;
    for (int ki = 0; ki < SS; ++ki) a += scr[qi][ki]*vs[ki][d];
    o[((size_t)(b*SS + qi))*RR + h*HDD + d] = a;
  }
}

// ---------------- K9b: out-proj [T,R], 4 tokens/block ----------------
__global__ void k_oproj(const float* __restrict__ ain, const float* __restrict__ w,
                        const float* __restrict__ bias, float* __restrict__ out){
  int t0 = blockIdx.x * 4, tid = threadIdx.x;
  __shared__ float sx[4][RR];
  for (int i = 0; i < 4; ++i) sx[i][tid] = ain[(size_t)(t0+i)*RR + tid];
  __syncthreads();
  float a[4] = {0,0,0,0};
  for (int d = 0; d < RR; ++d){
    float wv = w[(size_t)d*RR + tid];
    #pragma unroll
    for (int i = 0; i < 4; ++i) a[i] += sx[i][d]*wv;
  }
  float bb = bias[tid];
  #pragma unroll
  for (int i = 0; i < 4; ++i) out[(size_t)(t0+i)*RR + tid] = a[i] + bb;
}

// ---------------- K10: mean over S + predictor -> logits fp32 ----------------
__global__ void k_final(const float* __restrict__ oproj, const float* __restrict__ pw,
                        const float* __restrict__ pb, float* __restrict__ out){
  int b = blockIdx.x, tid = threadIdx.x;
  __shared__ float om[RR];
  float a = 0.f;
  for (int s = 0; s < SS; ++s) a += oproj[((size_t)(b*SS + s))*RR + tid];
  om[tid] = a * (1.f/SS);
  __syncthreads();
  if (tid < LL){
    float acc = pb[tid];
    for (int h = 0; h < RR; ++h) acc += om[h]*pw[h*LL + tid];
    out[b*LL + tid] = acc;
  }
}

extern "C" void kernel_launch(void* const* d_in, const int* in_sizes, int n_in,
                              void* d_out, int out_size, void* d_ws, size_t ws_size,
                              hipStream_t stream){
  (void)in_sizes; (void)n_in; (void)out_size; (void)ws_size;
  const float* emb      = (const float*)d_in[0];
  const int*   existing = (const int*)d_in[1];
  const float* mt       = (const float*)d_in[2];
  const float* dpe_w0   = (const float*)d_in[3];
  const float* dpe_b0   = (const float*)d_in[4];
  const float* dpe_w1   = (const float*)d_in[5];
  const float* dpe_b1   = (const float*)d_in[6];
  const float* dpe_w2   = (const float*)d_in[7];
  const float* dpe_b2   = (const float*)d_in[8];
  const float* dpe_wo   = (const float*)d_in[9];
  const float* dpe_bo   = (const float*)d_in[10];
  const float* dpe_lng  = (const float*)d_in[11];
  const float* dpe_lnb  = (const float*)d_in[12];
  const float* fus_w1c  = (const float*)d_in[13];
  const float* fus_w1p  = (const float*)d_in[14];
  const float* fus_b1   = (const float*)d_in[15];
  const float* fus_w2   = (const float*)d_in[16];
  const float* fus_b2   = (const float*)d_in[17];
  const float* gate_w1c = (const float*)d_in[18];
  const float* gate_w1p = (const float*)d_in[19];
  const float* gate_b1  = (const float*)d_in[20];
  const float* gate_w2  = (const float*)d_in[21];
  const float* gate_b2  = (const float*)d_in[22];
  const float* exp_lng  = (const float*)d_in[23];
  const float* exp_lnb  = (const float*)d_in[24];
  const float* rtr_w1   = (const float*)d_in[25];
  const float* rtr_b1   = (const float*)d_in[26];
  const float* rtr_w2   = (const float*)d_in[27];
  const float* rtr_b2   = (const float*)d_in[28];
  const float* red_w1   = (const float*)d_in[29];
  const float* red_b1   = (const float*)d_in[30];
  const float* red_w2   = (const float*)d_in[31];
  const float* red_b2   = (const float*)d_in[32];
  const float* red_lng  = (const float*)d_in[33];
  const float* red_lnb  = (const float*)d_in[34];
  const float* qkv_w    = (const float*)d_in[35];
  const float* qkv_b    = (const float*)d_in[36];
  const float* out_w    = (const float*)d_in[37];
  const float* out_b    = (const float*)d_in[38];
  const float* pred_w   = (const float*)d_in[39];
  const float* pred_b   = (const float*)d_in[40];
  float* out = (float*)d_out;

  // workspace layout (floats)
  float* wsf = (float*)d_ws;
  size_t off = 0;
  float* ctx  = wsf + off; off += (size_t)BB*DD;       // 393216
  float* pos  = wsf + off; off += (size_t)SS*EE*DD;    // 141312
  float* posF = wsf + off; off += (size_t)SS*EE*RR;    // 47104
  float* posG = wsf + off; off += (size_t)SS*EE*RR;    // 47104
  float* rtrD = wsf + off; off += (size_t)SS*RR;       // 5888
  float* ctxF = wsf + off; off += (size_t)BB*EE*RR;    // 1048576
  float* ctxG = wsf + off; off += (size_t)BB*EE*RR;    // 1048576
  float* rtrC = wsf + off; off += (size_t)BB*RR;       // 131072
  float* topv = wsf + off; off += (size_t)TT*2;        // 23552
  int*   topi = (int*)(wsf + off); off += (size_t)TT*2;
  float* sec  = wsf + off; off += (size_t)TT*DD;       // 9043968 (reused for q,k,v)
  float* x1   = wsf + off; off += (size_t)TT*HH2;      // 4521984 (reused for attn out)
  float* xr   = wsf + off; off += (size_t)TT*RR;       // 3014656 (reused for oproj)
  // buffer reuse after their consumers ran:
  float* q = sec;                 // T*R
  float* k = sec + (size_t)TT*RR; // T*R
  float* v = sec + (size_t)2*TT*RR;
  float* attnout = x1;            // T*R <= T*H2
  float* oproj   = xr;            // T*R

  k_context<<<BB, 256, 0, stream>>>(emb, existing, ctx);
  k_pos    <<<SS*EE, 256, 0, stream>>>(mt, dpe_w0, dpe_b0, dpe_w1, dpe_b1, dpe_w2, dpe_b2,
                                       dpe_wo, dpe_bo, dpe_lng, dpe_lnb, pos);
  k_posFG  <<<SS*EE, 256, 0, stream>>>(pos, fus_w1p, gate_w1p, posF, posG);
  k_rtrD   <<<SS, 256, 0, stream>>>(mt, rtr_w1, rtrD);
  k_ctxFG  <<<(BB/8)*EE, 256, 0, stream>>>(ctx, fus_w1c, gate_w1c, ctxF, ctxG);
  k_rtrC   <<<BB/8, 256, 0, stream>>>(ctx, rtr_w1, rtrC);
  k_router <<<TT, 256, 0, stream>>>(rtrD, rtrC, rtr_b1, rtr_w2, rtr_b2, topv, topi);
  k_sec    <<<TT, 256, 0, stream>>>(emb, existing, ctx, ctxF, ctxG, posF, posG,
                                    fus_b1, fus_w2, fus_b2, gate_b1, gate_w2, gate_b2,
                                    exp_lng, exp_lnb, topv, topi, sec);
  k_red1   <<<TT/4, 384, 0, stream>>>(sec, red_w1, red_b1, x1);
  k_red2   <<<TT/4, 256, 0, stream>>>(x1, red_w2, red_b2, red_lng, red_lnb, xr);
  k_qkv    <<<TT/4, 256, 0, stream>>>(xr, qkv_w, qkv_b, q, k, v);
  k_attn   <<<BB*NHH, 256, 0, stream>>>(q, k, v, attnout);
  k_oproj  <<<TT/4, 256, 0, stream>>>(attnout, out_w, out_b, oproj);
  k_final  <<<BB, 256, 0, stream>>>(oproj, pred_w, pred_b, out);
}